// Round 2
// baseline (8192.056 us; speedup 1.0000x reference)
//
#include <hip/hip_runtime.h>
#include <hip/hip_bf16.h>

// Swin window attention, B=4, DIM=192, 256x256, WS=8, SHIFT=4, HEADS=6, HD=32
#define IMG 256
#define DIMC 192
#define NHEADS 6
#define HDIM 32
#define SHIFTV 4
#define SCALEV 0.17677669529663687f

#define QW_N (576*192)
#define QB_N 576
#define PW_N (192*192)
#define PB_N 192
#define RPE_N (225*6)
#define OFF_QW 0
#define OFF_QB (OFF_QW+QW_N)
#define OFF_PW (OFF_QB+QB_N)
#define OFF_PB (OFF_PW+PW_N)
#define OFF_RPE (OFF_PB+PB_N)
#define WTOT (OFF_RPE+RPE_N)   // 149574 floats

// LDS layout (floats): xs[64][196] | qbuf[64][36] kbuf[64][36] vbuf[64][36] | oall[64][196]
// attn[64][68] overlays qbuf+kbuf (4352 <= 4608); ych[64][69] overlays same region after heads.
#define XSP 196
#define QP  36
#define AP  68
#define OP  196
#define YP  69
#define LDS_QBUF 12544
#define LDS_KBUF (LDS_QBUF+2304)
#define LDS_VBUF (LDS_KBUF+2304)
#define LDS_OALL (LDS_VBUF+2304)
#define LDS_TOT  (LDS_OALL+12544)   // 32000 floats = 125 KiB

__device__ __forceinline__ float ldin(const void* p, long i, int isb) {
  if (isb) return __bfloat162float(((const __hip_bfloat16*)p)[i]);
  return ((const float*)p)[i];
}

// Decide whether input buffers are bf16-packed or fp32.
// Interpret low 16 bits of each u32 as a bf16: for a true fp32 buffer these are
// random mantissa bits -> uniform-random exponent -> clamped |v| mean ~8.
// For a bf16 buffer they are N(0,1) samples -> mean ~0.8. Threshold 2.0.
__global__ void detect_dtype(const unsigned int* __restrict__ x, int* __restrict__ flag) {
  float s = 0.f;
  for (int i = 0; i < 8; ++i) {
    unsigned int w = x[threadIdx.x + 256 * i];
    float v = __uint_as_float((w & 0xFFFFu) << 16);
    v = fabsf(v);
    if (!(v < 16.f)) v = 16.f;   // clamp, also catches NaN/Inf
    s += v;
  }
  __shared__ float red[256];
  red[threadIdx.x] = s;
  __syncthreads();
  for (int off = 128; off > 0; off >>= 1) {
    if ((int)threadIdx.x < off) red[threadIdx.x] += red[threadIdx.x + off];
    __syncthreads();
  }
  if (threadIdx.x == 0) flag[0] = (red[0] * (1.f / 2048.f) < 2.0f) ? 1 : 0;
}

// Convert all weight tensors to canonical fp32 in workspace.
__global__ void convert_weights(const void* __restrict__ qw, const void* __restrict__ qb,
                                const void* __restrict__ pw, const void* __restrict__ pb,
                                const void* __restrict__ rp, float* __restrict__ dst,
                                const int* __restrict__ flag) {
  const int isb = flag[0];
  for (int i = blockIdx.x * 256 + threadIdx.x; i < WTOT; i += gridDim.x * 256) {
    long j = i; const void* s;
    if (j < QW_N) { s = qw; }
    else { j -= QW_N;
      if (j < QB_N) { s = qb; }
      else { j -= QB_N;
        if (j < PW_N) { s = pw; }
        else { j -= PW_N;
          if (j < PB_N) { s = pb; }
          else { j -= PB_N; s = rp; }
        }
      }
    }
    dst[i] = ldin(s, j, isb);
  }
}

__global__ __launch_bounds__(256, 1) void swin_fused(
    const void* __restrict__ x, const float* __restrict__ wsf,
    void* __restrict__ out, const int* __restrict__ flag)
{
  __shared__ float lds[LDS_TOT];
  float* xs   = lds;
  float* qbuf = lds + LDS_QBUF;
  float* kbuf = lds + LDS_KBUF;
  float* vbuf = lds + LDS_VBUF;
  float* attn = lds + LDS_QBUF;   // overlay (q,k dead when written)
  float* oall = lds + LDS_OALL;
  float* ych  = lds + LDS_QBUF;   // overlay after heads loop

  const int tid = threadIdx.x;
  const int blk = blockIdx.x;
  const int b  = blk >> 10;
  const int wh = (blk >> 5) & 31;
  const int ww = blk & 31;
  const int isb = flag[0];

  const float* Wq = wsf + OFF_QW;
  const float* Bq = wsf + OFF_QB;
  const float* Pw = wsf + OFF_PW;
  const float* Pb = wsf + OFF_PB;
  const float* RP = wsf + OFF_RPE;

  // ---- stage rolled x window into xs[t][c] ----
  {
    const int tj = tid & 7, ti = (tid >> 3) & 7, cg = tid >> 6;
    const int gi = (wh * 8 + ti + SHIFTV) & 255;
    const int gj = (ww * 8 + tj + SHIFTV) & 255;
    const long pixbase = ((long)b * DIMC) * 65536 + (long)gi * 256 + gj;
    const int t = ti * 8 + tj;
    for (int cc = cg; cc < DIMC; cc += 4)
      xs[t * XSP + cc] = ldin(x, pixbase + (long)cc * 65536, isb);
  }
  __syncthreads();

  for (int h = 0; h < NHEADS; ++h) {
    // ---- qkv for this head: thread = (t0 = tid>>3 in 0..31, d8 = tid&7) ----
    // rows handled: s in {0,1,2} x wg in {0..3}: d = d8 + 8*wg; tokens t0, t0+32
    {
      const int d8 = tid & 7, t0 = tid >> 3;
      float acc[2][12];
#pragma unroll
      for (int w = 0; w < 12; ++w) {
        const int s = w >> 2, wg = w & 3;
        const float bv = Bq[s * DIMC + h * HDIM + d8 + 8 * wg];
        acc[0][w] = bv; acc[1][w] = bv;
      }
      for (int c4 = 0; c4 < 48; ++c4) {
        float4 xv0 = *(const float4*)&xs[(t0) * XSP + c4 * 4];
        float4 xv1 = *(const float4*)&xs[(t0 + 32) * XSP + c4 * 4];
#pragma unroll
        for (int w = 0; w < 12; ++w) {
          const int s = w >> 2, wg = w & 3;
          const float4 wv = *(const float4*)&Wq[(long)(s * DIMC + h * HDIM + d8 + 8 * wg) * DIMC + c4 * 4];
          acc[0][w] += xv0.x * wv.x + xv0.y * wv.y + xv0.z * wv.z + xv0.w * wv.w;
          acc[1][w] += xv1.x * wv.x + xv1.y * wv.y + xv1.z * wv.z + xv1.w * wv.w;
        }
      }
#pragma unroll
      for (int w = 0; w < 12; ++w) {
        const int s = w >> 2, wg = w & 3;
        float* dst = (s == 0) ? qbuf : (s == 1) ? kbuf : vbuf;
        dst[(t0) * QP + d8 + 8 * wg] = acc[0][w];
        dst[(t0 + 32) * QP + d8 + 8 * wg] = acc[1][w];
      }
    }
    __syncthreads();

    // ---- scores: thread = (qq = tid>>4 in 0..15, kk = tid&15) ----
    // q rows: qq + 16*i ; k rows: kk + 16*j  (spread to limit LDS bank conflicts)
    {
      const int qq = tid >> 4, kk = tid & 15;
      float sc[4][4];
#pragma unroll
      for (int i = 0; i < 4; ++i)
#pragma unroll
        for (int j = 0; j < 4; ++j) sc[i][j] = 0.f;

      for (int d4 = 0; d4 < 8; ++d4) {
        float4 qv[4], kv[4];
#pragma unroll
        for (int i = 0; i < 4; ++i) qv[i] = *(const float4*)&qbuf[(qq + 16 * i) * QP + d4 * 4];
#pragma unroll
        for (int j = 0; j < 4; ++j) kv[j] = *(const float4*)&kbuf[(kk + 16 * j) * QP + d4 * 4];
#pragma unroll
        for (int i = 0; i < 4; ++i)
#pragma unroll
          for (int j = 0; j < 4; ++j)
            sc[i][j] += qv[i].x * kv[j].x + qv[i].y * kv[j].y + qv[i].z * kv[j].z + qv[i].w * kv[j].w;
      }

      const int rl_on = (wh == 31), cl_on = (ww == 31);
#pragma unroll
      for (int i = 0; i < 4; ++i) {
        const int q = qq + 16 * i; const int qi = q >> 3, qj = q & 7;
        const int lq = (rl_on ? (qi < 4 ? 1 : 2) : 0) * 3 + (cl_on ? (qj < 4 ? 1 : 2) : 0);
#pragma unroll
        for (int j = 0; j < 4; ++j) {
          const int k = kk + 16 * j; const int ki = k >> 3, kj = k & 7;
          const int lk = (rl_on ? (ki < 4 ? 1 : 2) : 0) * 3 + (cl_on ? (kj < 4 ? 1 : 2) : 0);
          const float v = sc[i][j] * SCALEV + RP[((qi - ki + 7) * 15 + (qj - kj + 7)) * 6 + h];
          sc[i][j] = (lq == lk) ? v : -1e30f;
        }
      }

      // softmax per q-row across the 16 kk-lanes
#pragma unroll
      for (int i = 0; i < 4; ++i) {
        float m = fmaxf(fmaxf(sc[i][0], sc[i][1]), fmaxf(sc[i][2], sc[i][3]));
        m = fmaxf(m, __shfl_xor(m, 1)); m = fmaxf(m, __shfl_xor(m, 2));
        m = fmaxf(m, __shfl_xor(m, 4)); m = fmaxf(m, __shfl_xor(m, 8));
        float s = 0.f;
#pragma unroll
        for (int j = 0; j < 4; ++j) { sc[i][j] = __expf(sc[i][j] - m); s += sc[i][j]; }
        s += __shfl_xor(s, 1); s += __shfl_xor(s, 2); s += __shfl_xor(s, 4); s += __shfl_xor(s, 8);
        const float inv = 1.f / s;
#pragma unroll
        for (int j = 0; j < 4; ++j) sc[i][j] *= inv;
      }

      __syncthreads();   // q/k fully consumed; safe to overwrite with attn
#pragma unroll
      for (int i = 0; i < 4; ++i)
#pragma unroll
        for (int j = 0; j < 4; ++j)
          attn[(qq + 16 * i) * AP + kk + 16 * j] = sc[i][j];
    }
    __syncthreads();

    // ---- PV: thread = (qp = tid>>3 in 0..31, dg = tid&7) ; q rows qp, qp+32 ; d = dg*4.. ----
    {
      const int qp = tid >> 3, dg = tid & 7;
      float o[2][4] = {{0.f,0.f,0.f,0.f},{0.f,0.f,0.f,0.f}};
      for (int k4 = 0; k4 < 16; ++k4) {
        float4 av0 = *(const float4*)&attn[(qp) * AP + k4 * 4];
        float4 av1 = *(const float4*)&attn[(qp + 32) * AP + k4 * 4];
#pragma unroll
        for (int kk2 = 0; kk2 < 4; ++kk2) {
          const float4 vv = *(const float4*)&vbuf[(k4 * 4 + kk2) * QP + dg * 4];
          const float a0 = (kk2 == 0) ? av0.x : (kk2 == 1) ? av0.y : (kk2 == 2) ? av0.z : av0.w;
          const float a1 = (kk2 == 0) ? av1.x : (kk2 == 1) ? av1.y : (kk2 == 2) ? av1.z : av1.w;
          o[0][0] += a0 * vv.x; o[0][1] += a0 * vv.y; o[0][2] += a0 * vv.z; o[0][3] += a0 * vv.w;
          o[1][0] += a1 * vv.x; o[1][1] += a1 * vv.y; o[1][2] += a1 * vv.z; o[1][3] += a1 * vv.w;
        }
      }
      *(float4*)&oall[(qp) * OP + h * HDIM + dg * 4] = make_float4(o[0][0], o[0][1], o[0][2], o[0][3]);
      *(float4*)&oall[(qp + 32) * OP + h * HDIM + dg * 4] = make_float4(o[1][0], o[1][1], o[1][2], o[1][3]);
    }
    __syncthreads();
  } // heads

  // ---- projection: 3 chunks of 64 output channels ----
  // thread = (tg = tid>>4 in 0..15, ek = tid&15); tokens tg+16*i, channels ec + ek + 16*j
  for (int ec = 0; ec < DIMC; ec += 64) {
    const int tg = tid >> 4, ek = tid & 15;
    float acc[4][4];
#pragma unroll
    for (int j = 0; j < 4; ++j) {
      const float bv = Pb[ec + ek + 16 * j];
#pragma unroll
      for (int i = 0; i < 4; ++i) acc[i][j] = bv;
    }
    for (int f4 = 0; f4 < 48; ++f4) {
      float4 av[4];
#pragma unroll
      for (int i = 0; i < 4; ++i) av[i] = *(const float4*)&oall[(tg + 16 * i) * OP + f4 * 4];
#pragma unroll
      for (int j = 0; j < 4; ++j) {
        const float4 wv = *(const float4*)&Pw[(long)(ec + ek + 16 * j) * DIMC + f4 * 4];
#pragma unroll
        for (int i = 0; i < 4; ++i)
          acc[i][j] += av[i].x * wv.x + av[i].y * wv.y + av[i].z * wv.z + av[i].w * wv.w;
      }
    }
    __syncthreads();  // ych region (qbuf overlay) free: previous use consumed
#pragma unroll
    for (int i = 0; i < 4; ++i)
#pragma unroll
      for (int j = 0; j < 4; ++j)
        ych[(tg + 16 * i) * YP + ek + 16 * j] = acc[i][j];
    __syncthreads();

    // cooperative store: lane t2 = tid&63 -> pixel; e_l loops over chunk
    {
      const int t2 = tid & 63, sub = tid >> 6;
      const int ti = t2 >> 3, tj = t2 & 7;
      const int gi = (wh * 8 + ti + SHIFTV) & 255;
      const int gj = (ww * 8 + tj + SHIFTV) & 255;
      for (int ii = 0; ii < 16; ++ii) {
        const int e_l = sub * 16 + ii;
        const float val = ych[t2 * YP + e_l];
        const long oidx = ((long)(b * DIMC + ec + e_l)) * 65536 + (long)gi * 256 + gj;
        if (isb) ((__hip_bfloat16*)out)[oidx] = __float2bfloat16(val);
        else ((float*)out)[oidx] = val;
      }
    }
    __syncthreads();
  }
}

extern "C" void kernel_launch(void* const* d_in, const int* in_sizes, int n_in,
                              void* d_out, int out_size, void* d_ws, size_t ws_size,
                              hipStream_t stream) {
  const void* x  = d_in[0];
  const void* qw = d_in[1];
  const void* qb = d_in[2];
  const void* pw = d_in[3];
  const void* pb = d_in[4];
  const void* rp = d_in[5];

  int* flag = (int*)d_ws;
  float* wsf = (float*)d_ws + 64;

  detect_dtype<<<1, 256, 0, stream>>>((const unsigned int*)x, flag);
  convert_weights<<<(WTOT + 255) / 256, 256, 0, stream>>>(qw, qb, pw, pb, rp, wsf, flag);
  swin_fused<<<4096, 256, 0, stream>>>(x, wsf, d_out, flag);
}

// Round 3
// 696.301 us; speedup vs baseline: 11.7651x; 11.7651x over previous
//
#include <hip/hip_runtime.h>
#include <hip/hip_bf16.h>

// Swin window attention, B=4, DIM=192, 256x256, WS=8, SHIFT=4, HEADS=6, HD=32
// MFMA (16x16x32 bf16) rewrite. 1 block = 1 window, 4 waves, 2 blocks/CU.

typedef __bf16 bf16x8 __attribute__((ext_vector_type(8)));
typedef __bf16 bf16x4 __attribute__((ext_vector_type(4)));
typedef float  f32x4  __attribute__((ext_vector_type(4)));

#define SCALEV 0.17677669529663687f

// workspace byte offsets
#define OFF_WQB 64                     // bf16 [576][192]
#define OFF_PWB 221248                 // bf16 [192][192]
#define OFF_BQ  294976                 // f32 [576]
#define OFF_PB  297280                 // f32 [192]
#define OFF_RPE 298048                 // f32 [225*6]

// LDS pads (elements); all row strides are 16B multiples, <=2-way bank alias
#define XSP 200
#define QKP 40
#define VTP 72
#define PPD 72
#define OAP 200
#define YCP 72

#define R1_VT 10240                    // qk2 = 4*64*40 = 10240 elems
#define R1_P  14848                    // vT2 = 64*72 = 4608
#define OALL_OFF 38912                 // region1 = 19456 elems * 2B
#define RPE_OFF  64512                 // + oall 64*200*2
#define SMEM_BYTES 69920               // + rpe 5400 -> 69912, pad

__device__ __forceinline__ float ldin(const void* p, long i, int isb) {
  if (isb) return __bfloat162float(((const __hip_bfloat16*)p)[i]);
  return ((const float*)p)[i];
}

// bf16-vs-fp32 input detection: low 16 bits of u32 as bf16 -> N(0,1) samples
// (mean |v| ~0.8) if buffer is bf16, uniform-random exponents (clamped mean ~8)
// if fp32 mantissa bits.
__global__ void detect_dtype(const unsigned int* __restrict__ x, int* __restrict__ flag) {
  float s = 0.f;
  for (int i = 0; i < 8; ++i) {
    unsigned int w = x[threadIdx.x + 256 * i];
    float v = __uint_as_float((w & 0xFFFFu) << 16);
    v = fabsf(v);
    if (!(v < 16.f)) v = 16.f;
    s += v;
  }
  __shared__ float red[256];
  red[threadIdx.x] = s;
  __syncthreads();
  for (int off = 128; off > 0; off >>= 1) {
    if ((int)threadIdx.x < off) red[threadIdx.x] += red[threadIdx.x + off];
    __syncthreads();
  }
  if (threadIdx.x == 0) flag[0] = (red[0] * (1.f / 2048.f) < 2.0f) ? 1 : 0;
}

__global__ void convert_weights(const void* __restrict__ qw, const void* __restrict__ qb,
                                const void* __restrict__ pw, const void* __restrict__ pb,
                                const void* __restrict__ rp,
                                unsigned char* __restrict__ ws,
                                const int* __restrict__ flag) {
  const int isb = flag[0];
  __bf16* Wqb = (__bf16*)(ws + OFF_WQB);
  __bf16* Pwb = (__bf16*)(ws + OFF_PWB);
  float*  Bqf = (float*)(ws + OFF_BQ);
  float*  Pbf = (float*)(ws + OFF_PB);
  float*  Rpf = (float*)(ws + OFF_RPE);
  const int i0 = blockIdx.x * 256 + threadIdx.x;
  const int st = gridDim.x * 256;
  for (int i = i0; i < 576 * 192; i += st) Wqb[i] = (__bf16)ldin(qw, i, isb);
  for (int i = i0; i < 192 * 192; i += st) Pwb[i] = (__bf16)ldin(pw, i, isb);
  if (i0 < 576)  Bqf[i0] = ldin(qb, i0, isb);
  if (i0 < 192)  Pbf[i0] = ldin(pb, i0, isb);
  if (i0 < 1350) Rpf[i0] = ldin(rp, i0, isb);
}

__global__ __launch_bounds__(256, 2) void swin_mfma(
    const void* __restrict__ x, const unsigned char* __restrict__ ws,
    void* __restrict__ out, const int* __restrict__ flag)
{
  __shared__ __align__(16) unsigned char smem[SMEM_BYTES];
  __bf16* r1   = (__bf16*)smem;              // xs | {qk2,vT2,P} | ych overlays
  __bf16* oall = (__bf16*)(smem + OALL_OFF); // [64][OAP]
  float*  rpel = (float*)(smem + RPE_OFF);   // [225*6]

  const __bf16* Wqb = (const __bf16*)(ws + OFF_WQB);
  const __bf16* Pwb = (const __bf16*)(ws + OFF_PWB);
  const float*  Bqf = (const float*)(ws + OFF_BQ);
  const float*  Pbf = (const float*)(ws + OFF_PB);
  const float*  Rpf = (const float*)(ws + OFF_RPE);

  const int tid = threadIdx.x;
  const int wv  = tid >> 6;
  const int ln  = tid & 63;
  const int col = ln & 15;       // MFMA n-col (B/D) or m-row (A)
  const int g   = ln >> 4;       // k-group (A/B), row-group (D)
  const int blk = blockIdx.x;
  const int bb = blk >> 10, wh = (blk >> 5) & 31, ww = blk & 31;
  const int isb = flag[0];

  // ---- stage rpe table ----
  for (int i = tid; i < 1350; i += 256) rpel[i] = Rpf[i];

  // ---- stage rolled window to xs[t][c] (bf16), 2 tokens/lane packed ----
  {
    const int half = ln >> 5, s5 = ln & 31;
    const int ti = s5 >> 2, tj2 = (s5 & 3) * 2;
    const int t0 = ti * 8 + tj2;
    const int gi = (wh * 8 + ti + 4) & 255;
    const int gj = (ww * 8 + tj2 + 4) & 255;   // even start; pair never wraps
    const long pix = (long)gi * 256 + gj;
    if (isb) {
      const unsigned short* xb = (const unsigned short*)x;
      for (int it = 0; it < 24; ++it) {
        const int c = wv * 48 + it * 2 + half;
        unsigned int w2 = *(const unsigned int*)(xb + (((long)(bb * 192 + c)) << 16) + pix);
        r1[t0 * XSP + c]       = __builtin_bit_cast(__bf16, (unsigned short)(w2 & 0xFFFFu));
        r1[(t0 + 1) * XSP + c] = __builtin_bit_cast(__bf16, (unsigned short)(w2 >> 16));
      }
    } else {
      const float* xf = (const float*)x;
      for (int it = 0; it < 24; ++it) {
        const int c = wv * 48 + it * 2 + half;
        float2 f2 = *(const float2*)(xf + (((long)(bb * 192 + c)) << 16) + pix);
        r1[t0 * XSP + c]       = (__bf16)f2.x;
        r1[(t0 + 1) * XSP + c] = (__bf16)f2.y;
      }
    }
  }
  __syncthreads();

  // ---- cache all A-fragments (window activations) in registers ----
  bf16x8 xa[4][6];
#pragma unroll
  for (int mt = 0; mt < 4; ++mt)
#pragma unroll
    for (int kc = 0; kc < 6; ++kc)
      xa[mt][kc] = *(const bf16x8*)&r1[(mt * 16 + col) * XSP + kc * 32 + g * 8];
  __syncthreads();   // xs region now dead -> reused below

  __bf16* qk2 = r1;            // [(s*2+hi)*64 + tok][QKP]  s:0=q,1=k
  __bf16* vT2 = r1 + R1_VT;    // [dglob 0..63][VTP] transposed V (2 heads)
  __bf16* Pl  = r1 + R1_P;     // [tok][PPD]

  const int rl = (wh == 31), cl = (ww == 31);

  for (int hp = 0; hp < 3; ++hp) {
    const int h0 = hp * 2;
    // ---- qkv GEMM for heads h0,h0+1: 12 n-tiles, 3 per wave ----
#pragma unroll
    for (int nt3 = 0; nt3 < 3; ++nt3) {
      const int nt = wv * 3 + nt3;
      const int sect = nt >> 2;            // 0=q,1=k,2=v (uniform per wave)
      const int ntl = nt & 3;
      const int orow = sect * 192 + h0 * 32 + ntl * 16 + col;  // Wq row = out ch
      const float bv = Bqf[orow];
      f32x4 acc[4];
#pragma unroll
      for (int mt = 0; mt < 4; ++mt) acc[mt] = (f32x4){bv, bv, bv, bv};
      const __bf16* wrow = Wqb + (long)orow * 192 + g * 8;
#pragma unroll
      for (int kc = 0; kc < 6; ++kc) {
        bf16x8 bf = *(const bf16x8*)(wrow + kc * 32);
#pragma unroll
        for (int mt = 0; mt < 4; ++mt)
          acc[mt] = __builtin_amdgcn_mfma_f32_16x16x32_bf16(xa[mt][kc], bf, acc[mt], 0, 0, 0);
      }
      if (sect < 2) {          // q or k -> [tok][d] layout
        const int hi = ntl >> 1, dl = (ntl & 1) * 16 + col;
        __bf16* dst = qk2 + (sect * 2 + hi) * (64 * QKP) + dl;
#pragma unroll
        for (int mt = 0; mt < 4; ++mt)
#pragma unroll
          for (int r = 0; r < 4; ++r)
            dst[(mt * 16 + g * 4 + r) * QKP] = (__bf16)acc[mt][r];
      } else {                 // v -> transposed [d][tok], packed b64 writes
        const int dg = ntl * 16 + col;     // 0..63 spans both heads
#pragma unroll
        for (int mt = 0; mt < 4; ++mt) {
          bf16x4 pk = { (__bf16)acc[mt][0], (__bf16)acc[mt][1],
                        (__bf16)acc[mt][2], (__bf16)acc[mt][3] };
          *(bf16x4*)&vT2[dg * VTP + mt * 16 + g * 4] = pk;
        }
      }
    }
    __syncthreads();

    for (int hx = 0; hx < 2; ++hx) {
      const int h = h0 + hx;
      // ---- S = q k^T (wave owns q-rows 16wv..16wv+15; K=32 = 1 MFMA) ----
      bf16x8 aq = *(const bf16x8*)&qk2[(hx * 64 + wv * 16 + col) * QKP + g * 8];
      f32x4 s[4];
#pragma unroll
      for (int nt = 0; nt < 4; ++nt) {
        bf16x8 bk = *(const bf16x8*)&qk2[((2 + hx) * 64 + nt * 16 + col) * QKP + g * 8];
        s[nt] = __builtin_amdgcn_mfma_f32_16x16x32_bf16(aq, bk, (f32x4){0.f, 0.f, 0.f, 0.f}, 0, 0, 0);
      }
      // ---- scale + rpe + shift-mask + softmax; rows q = 16wv + 4g + r ----
#pragma unroll
      for (int r = 0; r < 4; ++r) {
        const int qt = wv * 16 + g * 4 + r;
        const int qi = qt >> 3, qj = qt & 7;
        const int lq = (rl ? (qi < 4 ? 1 : 2) : 0) * 3 + (cl ? (qj < 4 ? 1 : 2) : 0);
        float vv[4];
#pragma unroll
        for (int nt = 0; nt < 4; ++nt) {
          const int kt = nt * 16 + col;
          const int ki = kt >> 3, kj = kt & 7;
          const int lk = (rl ? (ki < 4 ? 1 : 2) : 0) * 3 + (cl ? (kj < 4 ? 1 : 2) : 0);
          float v = s[nt][r] * SCALEV + rpel[((qi - ki + 7) * 15 + (qj - kj + 7)) * 6 + h];
          vv[nt] = (lq == lk) ? v : -1e30f;
        }
        float m = fmaxf(fmaxf(vv[0], vv[1]), fmaxf(vv[2], vv[3]));
        m = fmaxf(m, __shfl_xor(m, 1)); m = fmaxf(m, __shfl_xor(m, 2));
        m = fmaxf(m, __shfl_xor(m, 4)); m = fmaxf(m, __shfl_xor(m, 8));
        float sum = 0.f;
#pragma unroll
        for (int nt = 0; nt < 4; ++nt) { vv[nt] = __expf(vv[nt] - m); sum += vv[nt]; }
        sum += __shfl_xor(sum, 1); sum += __shfl_xor(sum, 2);
        sum += __shfl_xor(sum, 4); sum += __shfl_xor(sum, 8);
        const float inv = 1.f / sum;
#pragma unroll
        for (int nt = 0; nt < 4; ++nt)
          Pl[qt * PPD + nt * 16 + col] = (__bf16)(vv[nt] * inv);
      }
      __syncthreads();
      // ---- O = P V  (A=P rows, B=vT rows; K=64 over 2 chunks) ----
      f32x4 o[2] = { (f32x4){0.f, 0.f, 0.f, 0.f}, (f32x4){0.f, 0.f, 0.f, 0.f} };
#pragma unroll
      for (int kc = 0; kc < 2; ++kc) {
        bf16x8 ap = *(const bf16x8*)&Pl[(wv * 16 + col) * PPD + kc * 32 + g * 8];
#pragma unroll
        for (int n2 = 0; n2 < 2; ++n2) {
          bf16x8 bv2 = *(const bf16x8*)&vT2[(hx * 32 + n2 * 16 + col) * VTP + kc * 32 + g * 8];
          o[n2] = __builtin_amdgcn_mfma_f32_16x16x32_bf16(ap, bv2, o[n2], 0, 0, 0);
        }
      }
#pragma unroll
      for (int n2 = 0; n2 < 2; ++n2)
#pragma unroll
        for (int r = 0; r < 4; ++r)
          oall[(wv * 16 + g * 4 + r) * OAP + h * 32 + n2 * 16 + col] = (__bf16)o[n2][r];
      __syncthreads();
    }
  }

  // ---- proj: wave owns 48 out-channels, loops all 4 M-tiles ----
  {
    f32x4 pacc[3][4];
#pragma unroll
    for (int n3 = 0; n3 < 3; ++n3) {
      const float bv = Pbf[wv * 48 + n3 * 16 + col];
#pragma unroll
      for (int mt = 0; mt < 4; ++mt) pacc[n3][mt] = (f32x4){bv, bv, bv, bv};
    }
#pragma unroll
    for (int kc = 0; kc < 6; ++kc) {
      bf16x8 af[4];
#pragma unroll
      for (int mt = 0; mt < 4; ++mt)
        af[mt] = *(const bf16x8*)&oall[(mt * 16 + col) * OAP + kc * 32 + g * 8];
#pragma unroll
      for (int n3 = 0; n3 < 3; ++n3) {
        bf16x8 bw = *(const bf16x8*)&Pwb[(long)(wv * 48 + n3 * 16 + col) * 192 + kc * 32 + g * 8];
#pragma unroll
        for (int mt = 0; mt < 4; ++mt)
          pacc[n3][mt] = __builtin_amdgcn_mfma_f32_16x16x32_bf16(af[mt], bw, pacc[n3][mt], 0, 0, 0);
      }
    }
    // D[tok][e] -> ych[e][tok] (region1 overlay; all PV reads done)
    __bf16* ych = r1;
#pragma unroll
    for (int n3 = 0; n3 < 3; ++n3) {
      const int e = wv * 48 + n3 * 16 + col;
#pragma unroll
      for (int mt = 0; mt < 4; ++mt) {
        bf16x4 pk = { (__bf16)pacc[n3][mt][0], (__bf16)pacc[n3][mt][1],
                      (__bf16)pacc[n3][mt][2], (__bf16)pacc[n3][mt][3] };
        *(bf16x4*)&ych[e * YCP + mt * 16 + g * 4] = pk;
      }
    }
  }
  __syncthreads();

  // ---- store: 2 channels/instr, 2 tokens/lane packed (16B row segments) ----
  {
    const int half = ln >> 5, s5 = ln & 31;
    const int ti = s5 >> 2, tj2 = (s5 & 3) * 2;
    const int t0 = ti * 8 + tj2;
    const int gi = (wh * 8 + ti + 4) & 255;
    const int gj = (ww * 8 + tj2 + 4) & 255;
    const long pix = (long)gi * 256 + gj;
    const __bf16* ych = r1;
    if (isb) {
      unsigned short* ob = (unsigned short*)out;
      for (int it = 0; it < 24; ++it) {
        const int e = wv * 48 + it * 2 + half;
        unsigned int lo = __builtin_bit_cast(unsigned short, ych[e * YCP + t0]);
        unsigned int hi = __builtin_bit_cast(unsigned short, ych[e * YCP + t0 + 1]);
        *(unsigned int*)(ob + (((long)(bb * 192 + e)) << 16) + pix) = lo | (hi << 16);
      }
    } else {
      float* of = (float*)out;
      for (int it = 0; it < 24; ++it) {
        const int e = wv * 48 + it * 2 + half;
        float2 f2 = { (float)ych[e * YCP + t0], (float)ych[e * YCP + t0 + 1] };
        *(float2*)(of + (((long)(bb * 192 + e)) << 16) + pix) = f2;
      }
    }
  }
}

extern "C" void kernel_launch(void* const* d_in, const int* in_sizes, int n_in,
                              void* d_out, int out_size, void* d_ws, size_t ws_size,
                              hipStream_t stream) {
  const void* x  = d_in[0];
  const void* qw = d_in[1];
  const void* qb = d_in[2];
  const void* pw = d_in[3];
  const void* pb = d_in[4];
  const void* rp = d_in[5];

  int* flag = (int*)d_ws;
  unsigned char* ws = (unsigned char*)d_ws;

  detect_dtype<<<1, 256, 0, stream>>>((const unsigned int*)x, flag);
  convert_weights<<<432, 256, 0, stream>>>(qw, qb, pw, pb, rp, ws, flag);
  swin_mfma<<<4096, 256, 0, stream>>>(x, ws, d_out, flag);
}